// Round 1
// baseline (1581.871 us; speedup 1.0000x reference)
//
#include <hip/hip_runtime.h>

// GraphSAGE layer: out = relu(h @ Ws^T + (scatter_mean(h,src,dst))@Wn^T + b)
// N=50000 nodes, E=800000 edges, dim 128.
constexpr int N_NODES_C = 50000;
constexpr int N_EDGES_C = 800000;
constexpr int DIM_C     = 128;

// ---------------------------------------------------------------------------
// K1: scatter-add h[src[e]] into acc[dst[e]].  32 lanes per edge, float4 per
// lane (32*4 = 128).  Atomics are device-scope f32 adds (global_atomic_add_f32
// on gfx950).
// ---------------------------------------------------------------------------
__global__ __launch_bounds__(256) void sage_scatter(
    const float* __restrict__ h, const int* __restrict__ src,
    const int* __restrict__ dst, float* __restrict__ acc)
{
  int t = blockIdx.x * 256 + threadIdx.x;
  int e = t >> 5;                  // edge index (32 lanes per edge)
  if (e >= N_EDGES_C) return;
  int c = (t & 31) << 2;           // feature offset, 4 floats per lane
  int s = src[e];
  int d = dst[e];
  const float4 v = *reinterpret_cast<const float4*>(h + (size_t)s * DIM_C + c);
  float* o = acc + (size_t)d * DIM_C + c;
  atomicAdd(o + 0, v.x);
  atomicAdd(o + 1, v.y);
  atomicAdd(o + 2, v.z);
  atomicAdd(o + 3, v.w);
}

// ---------------------------------------------------------------------------
// K2: fused dual-GEMM epilogue.
// Block: 256 threads, 16 node rows x 128 out cols.
// LDS: both W matrices [o][k] padded to 130 floats/row (bank = (2*o+k)%32:
//      per-k reads with o = cx+32j give 2-way bank aliasing = free), plus
//      h/m row tiles (broadcast reads, conflict-free).
// Micro-tile per thread: 2 rows x 4 cols (cols strided by 32).
// ---------------------------------------------------------------------------
constexpr int ROWS_C = 16;

__global__ __launch_bounds__(256) void sage_gemm(
    const float* __restrict__ h, const float* __restrict__ acc,
    const float* __restrict__ deg, const float* __restrict__ Wself,
    const float* __restrict__ Wneigh, const float* __restrict__ bias,
    float* __restrict__ out)
{
  __shared__ float Wl[2][DIM_C][DIM_C + 2];   // 133120 B
  __shared__ float hl[ROWS_C][DIM_C];         //   8192 B
  __shared__ float ml[ROWS_C][DIM_C];         //   8192 B  -> 149504 B total

  const int t = threadIdx.x;

  // Stage W (coalesced global scalar reads; LDS writes conflict-free: k fast).
  for (int idx = t; idx < DIM_C * DIM_C; idx += 256) {
    int o = idx >> 7, k = idx & 127;
    Wl[0][o][k] = Wself[idx];
    Wl[1][o][k] = Wneigh[idx];
  }

  // Stage h and mean (fold 1/deg here). 50000 % 16 == 0, no tail guard needed.
  const int row0 = blockIdx.x * ROWS_C;
  for (int idx = t; idx < ROWS_C * (DIM_C / 4); idx += 256) {
    int r  = idx >> 5;
    int k4 = (idx & 31) << 2;
    int n  = row0 + r;
    float4 hv = *reinterpret_cast<const float4*>(h   + (size_t)n * DIM_C + k4);
    float4 mv = *reinterpret_cast<const float4*>(acc + (size_t)n * DIM_C + k4);
    float id = 1.0f / deg[n];   // deg pre-clamped >= 1 in inputs
    mv.x *= id; mv.y *= id; mv.z *= id; mv.w *= id;
    *reinterpret_cast<float4*>(&hl[r][k4]) = hv;
    *reinterpret_cast<float4*>(&ml[r][k4]) = mv;
  }
  __syncthreads();

  const int cx = t & 31;       // col group: cols cx + 32j
  const int ry = t >> 5;       // 0..7
  const int r0 = ry * 2;       // 2 rows per thread

  float accr[2][4];
#pragma unroll
  for (int i = 0; i < 2; i++)
#pragma unroll
    for (int j = 0; j < 4; j++) accr[i][j] = 0.0f;

#pragma unroll 4
  for (int k = 0; k < DIM_C; k++) {
    float w0[4], w1[4];
#pragma unroll
    for (int j = 0; j < 4; j++) {
      w0[j] = Wl[0][cx + 32 * j][k];
      w1[j] = Wl[1][cx + 32 * j][k];
    }
#pragma unroll
    for (int i = 0; i < 2; i++) {
      float hv = hl[r0 + i][k];
      float mv = ml[r0 + i][k];
#pragma unroll
      for (int j = 0; j < 4; j++)
        accr[i][j] = fmaf(hv, w0[j], fmaf(mv, w1[j], accr[i][j]));
    }
  }

#pragma unroll
  for (int i = 0; i < 2; i++) {
    int n = row0 + r0 + i;
#pragma unroll
    for (int j = 0; j < 4; j++) {
      int o = cx + 32 * j;
      float v = accr[i][j] + bias[o];
      out[(size_t)n * DIM_C + o] = fmaxf(v, 0.0f);
    }
  }
}

// ---------------------------------------------------------------------------
extern "C" void kernel_launch(void* const* d_in, const int* in_sizes, int n_in,
                              void* d_out, int out_size, void* d_ws, size_t ws_size,
                              hipStream_t stream) {
  const float* h      = (const float*)d_in[0];
  const int*   src    = (const int*)d_in[1];
  const int*   dst    = (const int*)d_in[2];
  const float* deg    = (const float*)d_in[3];
  const float* Wself  = (const float*)d_in[4];
  const float* Wneigh = (const float*)d_in[5];
  const float* bias   = (const float*)d_in[6];
  float*       out    = (float*)d_out;
  float*       acc    = (float*)d_ws;   // 50000*128 f32 = 25.6 MB scratch

  // ws is re-poisoned to 0xAA before every timed call -> must zero each time.
  hipMemsetAsync(acc, 0, (size_t)N_NODES_C * DIM_C * sizeof(float), stream);

  sage_scatter<<<(N_EDGES_C * 32) / 256, 256, 0, stream>>>(h, src, dst, acc);
  sage_gemm<<<N_NODES_C / ROWS_C, 256, 0, stream>>>(h, acc, deg, Wself, Wneigh,
                                                    bias, out);
}

// Round 2
// 417.534 us; speedup vs baseline: 3.7886x; 3.7886x over previous
//
#include <hip/hip_runtime.h>

// GraphSAGE layer: out = relu(h @ Ws^T + (scatter_mean(h,src,dst))@Wn^T + b)
// N=50000 nodes, E=800000 edges, dim 128.
// R2: replace 102M-f32-atomic scatter (1344us, atomic-pipe bound) with
//     device-built CSR + per-node register gather (no f32 atomics).
constexpr int N_NODES_C = 50000;
constexpr int N_EDGES_C = 800000;
constexpr int DIM_C     = 128;

// Workspace layout (bytes). Round-1 run proved ws_size >= 25.6 MB; total here
// is ~29.4 MB.
//   [0)           acc   : float[N][128]   (mean-aggregated neighbors)
//   [OFF_CNT)     cnt   : int[N]          (in-degree histogram)
//   [OFF_CUR)     cur   : int[N]          (placement cursors)
//   [OFF_OFFS)    offs  : int[N+1]        (CSR row offsets)
//   [OFF_ESRC)    esrc  : int[E]          (src node id per CSR slot)
constexpr size_t OFF_CNT  = (size_t)N_NODES_C * DIM_C * 4;        // 25,600,000
constexpr size_t OFF_CUR  = OFF_CNT + (size_t)N_NODES_C * 4;
constexpr size_t OFF_OFFS = OFF_CUR + (size_t)N_NODES_C * 4;
constexpr size_t OFF_ESRC = OFF_OFFS + ((size_t)N_NODES_C + 8) * 4;

// --------------------------------------------------------------------------
// K1: in-degree histogram. 800k int atomics on 200KB (L2-resident).
// --------------------------------------------------------------------------
__global__ __launch_bounds__(256) void sage_hist(
    const int* __restrict__ dst, int* __restrict__ cnt)
{
  int e = blockIdx.x * 256 + threadIdx.x;
  atomicAdd(&cnt[dst[e]], 1);
}

// --------------------------------------------------------------------------
// K2: exclusive prefix scan of cnt[N] -> offs[N+1]. Single block, 1024 thr,
// shfl wave-scans (2 LDS rounds per 1024-chunk).
// --------------------------------------------------------------------------
__global__ __launch_bounds__(1024) void sage_scan(
    const int* __restrict__ cnt, int* __restrict__ offs)
{
  __shared__ int wsum[16];
  __shared__ int woff[16];
  __shared__ int carry_s;
  const int lane = threadIdx.x & 63;
  const int wid  = threadIdx.x >> 6;
  if (threadIdx.x == 0) carry_s = 0;
  __syncthreads();

  for (int base = 0; base < N_NODES_C; base += 1024) {
    int i = base + threadIdx.x;
    int v = (i < N_NODES_C) ? cnt[i] : 0;
    // wave-inclusive scan
    int x = v;
#pragma unroll
    for (int d = 1; d < 64; d <<= 1) {
      int y = __shfl_up(x, d, 64);
      if (lane >= d) x += y;
    }
    if (lane == 63) wsum[wid] = x;
    __syncthreads();
    if (wid == 0) {
      int s = (lane < 16) ? wsum[lane] : 0;
      int xs = s;
#pragma unroll
      for (int d = 1; d < 16; d <<= 1) {
        int y = __shfl_up(xs, d, 64);
        if (lane >= d) xs += y;
      }
      if (lane < 16) woff[lane] = xs - s;  // exclusive wave offset
    }
    __syncthreads();
    int incl = x + woff[wid];
    int c = carry_s;
    if (i < N_NODES_C) offs[i] = c + incl - v;  // exclusive
    __syncthreads();                             // all read carry_s first
    if (threadIdx.x == 1023) carry_s = c + incl; // block total so far
    __syncthreads();
  }
  if (threadIdx.x == 0) offs[N_NODES_C] = carry_s;  // == E
}

// --------------------------------------------------------------------------
// K3: place edges into CSR slots. 800k int atomics on cursors.
// --------------------------------------------------------------------------
__global__ __launch_bounds__(256) void sage_place(
    const int* __restrict__ src, const int* __restrict__ dst,
    const int* __restrict__ offs, int* __restrict__ cur,
    int* __restrict__ esrc)
{
  int e = blockIdx.x * 256 + threadIdx.x;
  int d = dst[e];
  int pos = offs[d] + atomicAdd(&cur[d], 1);
  esrc[pos] = src[e];
}

// --------------------------------------------------------------------------
// K4: gather-mean. 32 lanes per dst node, float4 per lane (32*4=128 cols).
// Sums h[src] rows in registers, folds 1/deg, writes acc once (no memset of
// acc needed: every element written).
// --------------------------------------------------------------------------
__global__ __launch_bounds__(256) void sage_gather(
    const float* __restrict__ h, const int* __restrict__ offs,
    const int* __restrict__ esrc, const float* __restrict__ deg,
    float* __restrict__ acc)
{
  int t = blockIdx.x * 256 + threadIdx.x;
  int n = t >> 5;                 // dst node
  int c = (t & 31) << 2;          // feature offset
  int begin = offs[n];
  int end   = offs[n + 1];

  float4 sum = make_float4(0.f, 0.f, 0.f, 0.f);
  int i = begin;
  for (; i + 1 < end; i += 2) {   // unroll-2 for MLP
    int s0 = esrc[i];
    int s1 = esrc[i + 1];
    float4 a = *reinterpret_cast<const float4*>(h + (size_t)s0 * DIM_C + c);
    float4 b = *reinterpret_cast<const float4*>(h + (size_t)s1 * DIM_C + c);
    sum.x += a.x + b.x; sum.y += a.y + b.y;
    sum.z += a.z + b.z; sum.w += a.w + b.w;
  }
  if (i < end) {
    int s0 = esrc[i];
    float4 a = *reinterpret_cast<const float4*>(h + (size_t)s0 * DIM_C + c);
    sum.x += a.x; sum.y += a.y; sum.z += a.z; sum.w += a.w;
  }
  float id = 1.0f / deg[n];
  sum.x *= id; sum.y *= id; sum.z *= id; sum.w *= id;
  *reinterpret_cast<float4*>(acc + (size_t)n * DIM_C + c) = sum;
}

// --------------------------------------------------------------------------
// K5: fused dual-GEMM epilogue (unchanged from R1 except deg already folded).
// Block: 256 threads, 16 node rows x 128 out cols, both W in LDS.
// --------------------------------------------------------------------------
constexpr int ROWS_C = 16;

__global__ __launch_bounds__(256) void sage_gemm(
    const float* __restrict__ h, const float* __restrict__ acc,
    const float* __restrict__ Wself, const float* __restrict__ Wneigh,
    const float* __restrict__ bias, float* __restrict__ out)
{
  __shared__ float Wl[2][DIM_C][DIM_C + 2];   // 133120 B
  __shared__ float hl[ROWS_C][DIM_C];         //   8192 B
  __shared__ float ml[ROWS_C][DIM_C];         //   8192 B

  const int t = threadIdx.x;

  for (int idx = t; idx < DIM_C * DIM_C; idx += 256) {
    int o = idx >> 7, k = idx & 127;
    Wl[0][o][k] = Wself[idx];
    Wl[1][o][k] = Wneigh[idx];
  }

  const int row0 = blockIdx.x * ROWS_C;
  for (int idx = t; idx < ROWS_C * (DIM_C / 4); idx += 256) {
    int r  = idx >> 5;
    int k4 = (idx & 31) << 2;
    int n  = row0 + r;
    float4 hv = *reinterpret_cast<const float4*>(h   + (size_t)n * DIM_C + k4);
    float4 mv = *reinterpret_cast<const float4*>(acc + (size_t)n * DIM_C + k4);
    *reinterpret_cast<float4*>(&hl[r][k4]) = hv;
    *reinterpret_cast<float4*>(&ml[r][k4]) = mv;
  }
  __syncthreads();

  const int cx = t & 31;
  const int ry = t >> 5;
  const int r0 = ry * 2;

  float accr[2][4];
#pragma unroll
  for (int i = 0; i < 2; i++)
#pragma unroll
    for (int j = 0; j < 4; j++) accr[i][j] = 0.0f;

#pragma unroll 4
  for (int k = 0; k < DIM_C; k++) {
    float w0[4], w1[4];
#pragma unroll
    for (int j = 0; j < 4; j++) {
      w0[j] = Wl[0][cx + 32 * j][k];
      w1[j] = Wl[1][cx + 32 * j][k];
    }
#pragma unroll
    for (int i = 0; i < 2; i++) {
      float hv = hl[r0 + i][k];
      float mv = ml[r0 + i][k];
#pragma unroll
      for (int j = 0; j < 4; j++)
        accr[i][j] = fmaf(hv, w0[j], fmaf(mv, w1[j], accr[i][j]));
    }
  }

#pragma unroll
  for (int i = 0; i < 2; i++) {
    int n = row0 + r0 + i;
#pragma unroll
    for (int j = 0; j < 4; j++) {
      int o = cx + 32 * j;
      float v = accr[i][j] + bias[o];
      out[(size_t)n * DIM_C + o] = fmaxf(v, 0.0f);
    }
  }
}

// --------------------------------------------------------------------------
extern "C" void kernel_launch(void* const* d_in, const int* in_sizes, int n_in,
                              void* d_out, int out_size, void* d_ws, size_t ws_size,
                              hipStream_t stream) {
  const float* h      = (const float*)d_in[0];
  const int*   src    = (const int*)d_in[1];
  const int*   dst    = (const int*)d_in[2];
  const float* deg    = (const float*)d_in[3];
  const float* Wself  = (const float*)d_in[4];
  const float* Wneigh = (const float*)d_in[5];
  const float* bias   = (const float*)d_in[6];
  float*       out    = (float*)d_out;

  char* ws   = (char*)d_ws;
  float* acc = (float*)ws;
  int*   cnt  = (int*)(ws + OFF_CNT);
  int*   cur  = (int*)(ws + OFF_CUR);
  int*   offs = (int*)(ws + OFF_OFFS);
  int*   esrc = (int*)(ws + OFF_ESRC);

  // Zero only cnt+cur (contiguous, 400KB). acc/offs/esrc fully overwritten.
  hipMemsetAsync(cnt, 0, 2 * (size_t)N_NODES_C * sizeof(int), stream);

  sage_hist <<<N_EDGES_C / 256, 256, 0, stream>>>(dst, cnt);
  sage_scan <<<1, 1024, 0, stream>>>(cnt, offs);
  sage_place<<<N_EDGES_C / 256, 256, 0, stream>>>(src, dst, offs, cur, esrc);
  sage_gather<<<(N_NODES_C * 32) / 256, 256, 0, stream>>>(h, offs, esrc, deg, acc);
  sage_gemm <<<N_NODES_C / ROWS_C, 256, 0, stream>>>(h, acc, Wself, Wneigh,
                                                     bias, out);
}

// Round 3
// 277.560 us; speedup vs baseline: 5.6992x; 1.5043x over previous
//
#include <hip/hip_runtime.h>

// GraphSAGE layer: out = relu(h @ Ws^T + (scatter_mean(h,src,dst)) @ Wn^T + b)
// N=50000, E=800000, dim 128.
// R3: (a) GEMM -> single fused K=256 bf16 MFMA GEMM (R2 gemm was 167us at 10%
//     occupancy, f32 VALU-bound); (b) gather reads/writes bf16 (halves its
//     205->410MB L2/L3 traffic). Harness compares at bf16 ulp granularity
//     (threshold 8 ulp = 0.0625), so bf16 inputs are safe.
constexpr int N_NODES_C = 50000;
constexpr int N_EDGES_C = 800000;
constexpr int DIM_C     = 128;

typedef __attribute__((ext_vector_type(8))) short short8;  // 8 bf16, 4 VGPRs
typedef __attribute__((ext_vector_type(4))) float f32x4;

// Workspace layout (bytes), total ~29.4 MB (R2 proved ws_size covers this):
//   [0)        h_bf16  : ushort[N][128]   12.8 MB
//   [OFF_ACC)  acc_bf16: ushort[N][128]   12.8 MB
//   [OFF_CNT)  cnt     : int[N]
//   [OFF_CUR)  cur     : int[N]
//   [OFF_OFFS) offs    : int[N+1] (padded)
//   [OFF_ESRC) esrc    : int[E]
constexpr size_t OFF_ACC  = (size_t)N_NODES_C * DIM_C * 2;          // 12,800,000
constexpr size_t OFF_CNT  = OFF_ACC + (size_t)N_NODES_C * DIM_C * 2;
constexpr size_t OFF_CUR  = OFF_CNT + (size_t)N_NODES_C * 4;
constexpr size_t OFF_OFFS = OFF_CUR + (size_t)N_NODES_C * 4;
constexpr size_t OFF_ESRC = OFF_OFFS + ((size_t)N_NODES_C + 4) * 4;

// round-to-nearest-even f32 -> bf16 bits (finite inputs only)
static __device__ __forceinline__ ushort f2bf(float f) {
  unsigned u = __float_as_uint(f);
  return (ushort)((u + 0x7FFFu + ((u >> 16) & 1u)) >> 16);
}
static __device__ __forceinline__ unsigned pack2(float a, float b) {
  return (unsigned)f2bf(a) | ((unsigned)f2bf(b) << 16);
}

// --------------------------------------------------------------------------
// K0: cast h f32 -> bf16. 8 elems/thread. 6.4M elems = 3125 blocks exactly.
// --------------------------------------------------------------------------
__global__ __launch_bounds__(256) void sage_cast(
    const float* __restrict__ h, ushort* __restrict__ hb)
{
  size_t i = ((size_t)blockIdx.x * 256 + threadIdx.x) * 8;
  float4 a = *reinterpret_cast<const float4*>(h + i);
  float4 b = *reinterpret_cast<const float4*>(h + i + 4);
  uint4 o;
  o.x = pack2(a.x, a.y); o.y = pack2(a.z, a.w);
  o.z = pack2(b.x, b.y); o.w = pack2(b.z, b.w);
  *reinterpret_cast<uint4*>(hb + i) = o;
}

// --------------------------------------------------------------------------
// K1: in-degree histogram (int atomics on 200KB, L2-resident).
// --------------------------------------------------------------------------
__global__ __launch_bounds__(256) void sage_hist(
    const int* __restrict__ dst, int* __restrict__ cnt)
{
  int e = blockIdx.x * 256 + threadIdx.x;
  atomicAdd(&cnt[dst[e]], 1);
}

// --------------------------------------------------------------------------
// K2: exclusive scan cnt[N] -> offs[N+1]. Single 1024-thread block.
// --------------------------------------------------------------------------
__global__ __launch_bounds__(1024) void sage_scan(
    const int* __restrict__ cnt, int* __restrict__ offs)
{
  __shared__ int wsum[16];
  __shared__ int woff[16];
  __shared__ int carry_s;
  const int lane = threadIdx.x & 63;
  const int wid  = threadIdx.x >> 6;
  if (threadIdx.x == 0) carry_s = 0;
  __syncthreads();

  for (int base = 0; base < N_NODES_C; base += 1024) {
    int i = base + threadIdx.x;
    int v = (i < N_NODES_C) ? cnt[i] : 0;
    int x = v;
#pragma unroll
    for (int d = 1; d < 64; d <<= 1) {
      int y = __shfl_up(x, d, 64);
      if (lane >= d) x += y;
    }
    if (lane == 63) wsum[wid] = x;
    __syncthreads();
    if (wid == 0) {
      int s = (lane < 16) ? wsum[lane] : 0;
      int xs = s;
#pragma unroll
      for (int d = 1; d < 16; d <<= 1) {
        int y = __shfl_up(xs, d, 64);
        if (lane >= d) xs += y;
      }
      if (lane < 16) woff[lane] = xs - s;
    }
    __syncthreads();
    int incl = x + woff[wid];
    int c = carry_s;
    if (i < N_NODES_C) offs[i] = c + incl - v;
    __syncthreads();
    if (threadIdx.x == 1023) carry_s = c + incl;
    __syncthreads();
  }
  if (threadIdx.x == 0) offs[N_NODES_C] = carry_s;
}

// --------------------------------------------------------------------------
// K3: place edges into CSR slots.
// --------------------------------------------------------------------------
__global__ __launch_bounds__(256) void sage_place(
    const int* __restrict__ src, const int* __restrict__ dst,
    const int* __restrict__ offs, int* __restrict__ cur,
    int* __restrict__ esrc)
{
  int e = blockIdx.x * 256 + threadIdx.x;
  int d = dst[e];
  int pos = offs[d] + atomicAdd(&cur[d], 1);
  esrc[pos] = src[e];
}

// --------------------------------------------------------------------------
// K4: gather-mean in bf16. 32 lanes per dst node, 4 bf16 (8B) per lane.
// f32 accumulate, fold 1/deg, write bf16 acc row once.
// --------------------------------------------------------------------------
__global__ __launch_bounds__(256) void sage_gather(
    const ushort* __restrict__ hb, const int* __restrict__ offs,
    const int* __restrict__ esrc, const float* __restrict__ deg,
    ushort* __restrict__ accb)
{
  int t = blockIdx.x * 256 + threadIdx.x;
  int n = t >> 5;
  int c = (t & 31) << 2;          // 4 bf16 per lane
  int begin = offs[n];
  int end   = offs[n + 1];

  float s0 = 0.f, s1 = 0.f, s2 = 0.f, s3 = 0.f;
  int i = begin;
  for (; i + 1 < end; i += 2) {
    int e0 = esrc[i], e1 = esrc[i + 1];
    uint2 a = *reinterpret_cast<const uint2*>(hb + (size_t)e0 * DIM_C + c);
    uint2 b = *reinterpret_cast<const uint2*>(hb + (size_t)e1 * DIM_C + c);
    s0 += __uint_as_float(a.x << 16)       + __uint_as_float(b.x << 16);
    s1 += __uint_as_float(a.x & 0xFFFF0000u) + __uint_as_float(b.x & 0xFFFF0000u);
    s2 += __uint_as_float(a.y << 16)       + __uint_as_float(b.y << 16);
    s3 += __uint_as_float(a.y & 0xFFFF0000u) + __uint_as_float(b.y & 0xFFFF0000u);
  }
  if (i < end) {
    int e0 = esrc[i];
    uint2 a = *reinterpret_cast<const uint2*>(hb + (size_t)e0 * DIM_C + c);
    s0 += __uint_as_float(a.x << 16);
    s1 += __uint_as_float(a.x & 0xFFFF0000u);
    s2 += __uint_as_float(a.y << 16);
    s3 += __uint_as_float(a.y & 0xFFFF0000u);
  }
  float id = 1.0f / deg[n];
  uint2 o;
  o.x = pack2(s0 * id, s1 * id);
  o.y = pack2(s2 * id, s3 * id);
  *reinterpret_cast<uint2*>(accb + (size_t)n * DIM_C + c) = o;
}

// --------------------------------------------------------------------------
// K5: fused bf16 MFMA GEMM, K=256 (k<128 from h_bf16, k>=128 from acc_bf16).
// Block = 256 thr (4 waves), 64 rows/block; wave w -> rows m0+w*16..+15.
// W staged in LDS as bf16 [128 n][256+8 k] (67.6 KB -> 2 blocks/CU).
// Per wave: 8 n-tiles x 8 k-steps of mfma_f32_16x16x32_bf16.
// Layouts (m89/m91-verified): A[m=lane&15][k=quad*8+j];
// B from W[n][k] with n=lane&15, k=quad*8+j; C/D col=lane&15, row=quad*4+reg.
// --------------------------------------------------------------------------
__global__ __launch_bounds__(256) void sage_gemm_mfma(
    const ushort* __restrict__ hb, const ushort* __restrict__ accb,
    const float* __restrict__ Wself, const float* __restrict__ Wneigh,
    const float* __restrict__ bias, float* __restrict__ out)
{
  __shared__ ushort Bl[DIM_C][256 + 8];   // 67,584 B
  __shared__ float  bias_l[DIM_C];

  const int t = threadIdx.x;

  // Stage W -> bf16 LDS. idx over 128 rows x 32 float4s.
  for (int idx = t; idx < DIM_C * 32; idx += 256) {
    int n  = idx >> 5;
    int k4 = (idx & 31) << 2;
    float4 ws4 = *reinterpret_cast<const float4*>(Wself  + n * DIM_C + k4);
    float4 wn4 = *reinterpret_cast<const float4*>(Wneigh + n * DIM_C + k4);
    *reinterpret_cast<uint2*>(&Bl[n][k4]) =
        make_uint2(pack2(ws4.x, ws4.y), pack2(ws4.z, ws4.w));
    *reinterpret_cast<uint2*>(&Bl[n][128 + k4]) =
        make_uint2(pack2(wn4.x, wn4.y), pack2(wn4.z, wn4.w));
  }
  if (t < DIM_C) bias_l[t] = bias[t];
  __syncthreads();

  const int lane = t & 63;
  const int w    = t >> 6;
  const int am   = lane & 15;   // row within 16-tile / col within C-tile
  const int q    = lane >> 4;   // quad 0..3
  const int m0   = blockIdx.x * 64 + w * 16;

  int r = m0 + am;
  if (r >= N_NODES_C) r = N_NODES_C - 1;   // clamp; stores guarded below
  const ushort* aph = hb   + (size_t)r * DIM_C + q * 8;
  const ushort* apa = accb + (size_t)r * DIM_C + q * 8;

  f32x4 acc[8];
#pragma unroll
  for (int nt = 0; nt < 8; nt++) acc[nt] = (f32x4){0.f, 0.f, 0.f, 0.f};

#pragma unroll
  for (int ks = 0; ks < 4; ks++) {
    short8 af = *reinterpret_cast<const short8*>(aph + ks * 32);
#pragma unroll
    for (int nt = 0; nt < 8; nt++) {
      short8 bf = *reinterpret_cast<const short8*>(&Bl[nt * 16 + am][ks * 32 + q * 8]);
      acc[nt] = __builtin_amdgcn_mfma_f32_16x16x32_bf16(af, bf, acc[nt], 0, 0, 0);
    }
  }
#pragma unroll
  for (int ks = 0; ks < 4; ks++) {
    short8 af = *reinterpret_cast<const short8*>(apa + ks * 32);
#pragma unroll
    for (int nt = 0; nt < 8; nt++) {
      short8 bf = *reinterpret_cast<const short8*>(&Bl[nt * 16 + am][128 + ks * 32 + q * 8]);
      acc[nt] = __builtin_amdgcn_mfma_f32_16x16x32_bf16(af, bf, acc[nt], 0, 0, 0);
    }
  }

#pragma unroll
  for (int nt = 0; nt < 8; nt++) {
    int col = nt * 16 + am;
    float bv = bias_l[col];
#pragma unroll
    for (int rr = 0; rr < 4; rr++) {
      int row = m0 + q * 4 + rr;
      if (row < N_NODES_C) {
        float v = acc[nt][rr] + bv;
        out[(size_t)row * DIM_C + col] = fmaxf(v, 0.f);
      }
    }
  }
}

// --------------------------------------------------------------------------
extern "C" void kernel_launch(void* const* d_in, const int* in_sizes, int n_in,
                              void* d_out, int out_size, void* d_ws, size_t ws_size,
                              hipStream_t stream) {
  const float* h      = (const float*)d_in[0];
  const int*   src    = (const int*)d_in[1];
  const int*   dst    = (const int*)d_in[2];
  const float* deg    = (const float*)d_in[3];
  const float* Wself  = (const float*)d_in[4];
  const float* Wneigh = (const float*)d_in[5];
  const float* bias   = (const float*)d_in[6];
  float*       out    = (float*)d_out;

  char* ws = (char*)d_ws;
  ushort* hb   = (ushort*)ws;
  ushort* accb = (ushort*)(ws + OFF_ACC);
  int*    cnt  = (int*)(ws + OFF_CNT);
  int*    cur  = (int*)(ws + OFF_CUR);
  int*    offs = (int*)(ws + OFF_OFFS);
  int*    esrc = (int*)(ws + OFF_ESRC);

  // Zero cnt+cur (contiguous 400KB); everything else fully overwritten.
  hipMemsetAsync(cnt, 0, 2 * (size_t)N_NODES_C * sizeof(int), stream);

  sage_cast  <<<(N_NODES_C * DIM_C) / (256 * 8), 256, 0, stream>>>(h, hb);
  sage_hist  <<<N_EDGES_C / 256, 256, 0, stream>>>(dst, cnt);
  sage_scan  <<<1, 1024, 0, stream>>>(cnt, offs);
  sage_place <<<N_EDGES_C / 256, 256, 0, stream>>>(src, dst, offs, cur, esrc);
  sage_gather<<<(N_NODES_C * 32) / 256, 256, 0, stream>>>(hb, offs, esrc, deg, accb);
  sage_gemm_mfma<<<(N_NODES_C + 63) / 64, 256, 0, stream>>>(hb, accb, Wself,
                                                            Wneigh, bias, out);
}

// Round 4
// 227.648 us; speedup vs baseline: 6.9488x; 1.2192x over previous
//
#include <hip/hip_runtime.h>

// GraphSAGE layer: out = relu(h @ Ws^T + (scatter_mean(h,src,dst)) @ Wn^T + b)
// N=50000, E=800000, dim 128.
// R4: (a) place partitioned by dst-range x XCD (R3: 55MB HBM write-amp from
//     cross-XCD line bouncing on 4B scatters); (b) scan 4 elems/thread
//     (13 iters vs 49); (c) cast+hist fused (independent work, one launch).
constexpr int N_NODES_C = 50000;
constexpr int N_EDGES_C = 800000;
constexpr int DIM_C     = 128;

typedef __attribute__((ext_vector_type(8))) short short8;  // 8 bf16, 4 VGPRs
typedef __attribute__((ext_vector_type(4))) float f32x4;

// Workspace layout (bytes), total ~29.4 MB:
//   [0)        h_bf16  : ushort[N][128]   12.8 MB
//   [OFF_ACC)  acc_bf16: ushort[N][128]   12.8 MB
//   [OFF_CNT)  cnt     : int[N]
//   [OFF_CUR)  cur     : int[N]
//   [OFF_OFFS) offs    : int[N+1] (padded; 16B-aligned for int4 stores)
//   [OFF_ESRC) esrc    : int[E]
constexpr size_t OFF_ACC  = (size_t)N_NODES_C * DIM_C * 2;          // 12,800,000
constexpr size_t OFF_CNT  = OFF_ACC + (size_t)N_NODES_C * DIM_C * 2;// 25,600,000
constexpr size_t OFF_CUR  = OFF_CNT + (size_t)N_NODES_C * 4;        // 25,800,000
constexpr size_t OFF_OFFS = OFF_CUR + (size_t)N_NODES_C * 4;        // 26,000,000 (16-aligned)
constexpr size_t OFF_ESRC = OFF_OFFS + ((size_t)N_NODES_C + 4) * 4; // 26,200,016 (16-aligned)

// round-to-nearest-even f32 -> bf16 bits (finite inputs only)
static __device__ __forceinline__ ushort f2bf(float f) {
  unsigned u = __float_as_uint(f);
  return (ushort)((u + 0x7FFFu + ((u >> 16) & 1u)) >> 16);
}
static __device__ __forceinline__ unsigned pack2(float a, float b) {
  return (unsigned)f2bf(a) | ((unsigned)f2bf(b) << 16);
}

// --------------------------------------------------------------------------
// K0: fused cast(h f32->bf16) + in-degree histogram.
// Blocks [0,3125): cast 8 elems/thread (3125*256*8 = 6.4M exactly).
// Blocks [3125,6250): hist, 1 edge/thread (3125*256 = 800k exactly).
// --------------------------------------------------------------------------
__global__ __launch_bounds__(256) void sage_cast_hist(
    const float* __restrict__ h, ushort* __restrict__ hb,
    const int* __restrict__ dst, int* __restrict__ cnt)
{
  int b = blockIdx.x;
  if (b < 3125) {
    size_t i = ((size_t)b * 256 + threadIdx.x) * 8;
    float4 a = *reinterpret_cast<const float4*>(h + i);
    float4 c = *reinterpret_cast<const float4*>(h + i + 4);
    uint4 o;
    o.x = pack2(a.x, a.y); o.y = pack2(a.z, a.w);
    o.z = pack2(c.x, c.y); o.w = pack2(c.z, c.w);
    *reinterpret_cast<uint4*>(hb + i) = o;
  } else {
    int e = (b - 3125) * 256 + threadIdx.x;
    atomicAdd(&cnt[dst[e]], 1);
  }
}

// --------------------------------------------------------------------------
// K1: exclusive scan cnt[N] -> offs[N+1]. Single 1024-thread block,
// 4 elems/thread via int4 (12500 groups = 13 iterations, no partial int4).
// --------------------------------------------------------------------------
__global__ __launch_bounds__(1024) void sage_scan(
    const int* __restrict__ cnt, int* __restrict__ offs)
{
  __shared__ int wsum[16];
  __shared__ int woff[16];
  __shared__ int carry_s;
  const int lane = threadIdx.x & 63;
  const int wid  = threadIdx.x >> 6;
  if (threadIdx.x == 0) carry_s = 0;
  __syncthreads();

  constexpr int NGROUP = N_NODES_C / 4;   // 12500
  for (int base = 0; base < NGROUP; base += 1024) {
    int g = base + threadIdx.x;
    int4 v = make_int4(0, 0, 0, 0);
    if (g < NGROUP) v = *reinterpret_cast<const int4*>(cnt + (size_t)g * 4);
    int tsum = v.x + v.y + v.z + v.w;
    int x = tsum;
#pragma unroll
    for (int d = 1; d < 64; d <<= 1) {
      int y = __shfl_up(x, d, 64);
      if (lane >= d) x += y;
    }
    if (lane == 63) wsum[wid] = x;
    __syncthreads();
    if (wid == 0) {
      int s = (lane < 16) ? wsum[lane] : 0;
      int xs = s;
#pragma unroll
      for (int d = 1; d < 16; d <<= 1) {
        int y = __shfl_up(xs, d, 64);
        if (lane >= d) xs += y;
      }
      if (lane < 16) woff[lane] = xs - s;
    }
    __syncthreads();
    int c = carry_s;
    int excl = c + woff[wid] + x - tsum;
    if (g < NGROUP) {
      int4 o;
      o.x = excl;
      o.y = o.x + v.x;
      o.z = o.y + v.y;
      o.w = o.z + v.z;
      *reinterpret_cast<int4*>(offs + (size_t)g * 4) = o;
    }
    __syncthreads();                           // all read carry_s first
    if (threadIdx.x == 1023) carry_s = c + woff[15] + x;  // x == wave15 total
    __syncthreads();
  }
  if (threadIdx.x == 0) offs[N_NODES_C] = carry_s;   // == E
}

// --------------------------------------------------------------------------
// K2: place edges into CSR slots, partitioned by dst-range x XCD.
// part = blockIdx&7 (MI300-family round-robin block->XCD heuristic; perf
// only, correct under any mapping). Each block scans a 4096-edge chunk and
// places only dsts in [part*6250, (part+1)*6250) -> all writes/atomics to a
// given esrc/cur region stay on one XCD's L2; lines write back once.
// --------------------------------------------------------------------------
constexpr int P_PARTS   = 8;
constexpr int NODES_PP  = N_NODES_C / P_PARTS;          // 6250
constexpr int EPT_PLACE = 16;
constexpr int EPB_PLACE = 256 * EPT_PLACE;              // 4096
constexpr int NCHUNK    = (N_EDGES_C + EPB_PLACE - 1) / EPB_PLACE;  // 196

__global__ __launch_bounds__(256) void sage_place(
    const int* __restrict__ src, const int* __restrict__ dst,
    const int* __restrict__ offs, int* __restrict__ cur,
    int* __restrict__ esrc)
{
  const int part  = blockIdx.x & (P_PARTS - 1);
  const int chunk = blockIdx.x >> 3;
  const int lo = part * NODES_PP;
  const int hi = lo + NODES_PP;
  const int base = chunk * EPB_PLACE;
#pragma unroll 4
  for (int i = 0; i < EPT_PLACE; i++) {
    int e = base + i * 256 + threadIdx.x;
    if (e < N_EDGES_C) {
      int d = dst[e];
      if (d >= lo && d < hi) {
        int pos = offs[d] + atomicAdd(&cur[d], 1);
        esrc[pos] = src[e];
      }
    }
  }
}

// --------------------------------------------------------------------------
// K3: gather-mean in bf16. 32 lanes per dst node, 4 bf16 (8B) per lane.
// f32 accumulate, fold 1/deg, write bf16 acc row once. Unroll-4 for MLP.
// --------------------------------------------------------------------------
__global__ __launch_bounds__(256) void sage_gather(
    const ushort* __restrict__ hb, const int* __restrict__ offs,
    const int* __restrict__ esrc, const float* __restrict__ deg,
    ushort* __restrict__ accb)
{
  int t = blockIdx.x * 256 + threadIdx.x;
  int n = t >> 5;
  int c = (t & 31) << 2;          // 4 bf16 per lane
  int begin = offs[n];
  int end   = offs[n + 1];

  float s0 = 0.f, s1 = 0.f, s2 = 0.f, s3 = 0.f;
  int i = begin;
  for (; i + 3 < end; i += 4) {
    int e0 = esrc[i], e1 = esrc[i + 1], e2 = esrc[i + 2], e3 = esrc[i + 3];
    uint2 a = *reinterpret_cast<const uint2*>(hb + (size_t)e0 * DIM_C + c);
    uint2 b = *reinterpret_cast<const uint2*>(hb + (size_t)e1 * DIM_C + c);
    uint2 d = *reinterpret_cast<const uint2*>(hb + (size_t)e2 * DIM_C + c);
    uint2 f = *reinterpret_cast<const uint2*>(hb + (size_t)e3 * DIM_C + c);
    s0 += __uint_as_float(a.x << 16) + __uint_as_float(b.x << 16)
        + __uint_as_float(d.x << 16) + __uint_as_float(f.x << 16);
    s1 += __uint_as_float(a.x & 0xFFFF0000u) + __uint_as_float(b.x & 0xFFFF0000u)
        + __uint_as_float(d.x & 0xFFFF0000u) + __uint_as_float(f.x & 0xFFFF0000u);
    s2 += __uint_as_float(a.y << 16) + __uint_as_float(b.y << 16)
        + __uint_as_float(d.y << 16) + __uint_as_float(f.y << 16);
    s3 += __uint_as_float(a.y & 0xFFFF0000u) + __uint_as_float(b.y & 0xFFFF0000u)
        + __uint_as_float(d.y & 0xFFFF0000u) + __uint_as_float(f.y & 0xFFFF0000u);
  }
  for (; i < end; i++) {
    int e0 = esrc[i];
    uint2 a = *reinterpret_cast<const uint2*>(hb + (size_t)e0 * DIM_C + c);
    s0 += __uint_as_float(a.x << 16);
    s1 += __uint_as_float(a.x & 0xFFFF0000u);
    s2 += __uint_as_float(a.y << 16);
    s3 += __uint_as_float(a.y & 0xFFFF0000u);
  }
  float id = 1.0f / deg[n];
  uint2 o;
  o.x = pack2(s0 * id, s1 * id);
  o.y = pack2(s2 * id, s3 * id);
  *reinterpret_cast<uint2*>(accb + (size_t)n * DIM_C + c) = o;
}

// --------------------------------------------------------------------------
// K4: fused bf16 MFMA GEMM, K=256 (k<128 from h_bf16, k>=128 from acc_bf16).
// Block = 256 thr (4 waves), 64 rows/block. W staged bf16 in LDS (67.6 KB).
// Layouts (m89/m91-verified): A[m=lane&15][k=quad*8+j];
// B from W[n][k] with n=lane&15, k=quad*8+j; C/D col=lane&15, row=quad*4+reg.
// --------------------------------------------------------------------------
__global__ __launch_bounds__(256) void sage_gemm_mfma(
    const ushort* __restrict__ hb, const ushort* __restrict__ accb,
    const float* __restrict__ Wself, const float* __restrict__ Wneigh,
    const float* __restrict__ bias, float* __restrict__ out)
{
  __shared__ ushort Bl[DIM_C][256 + 8];   // 67,584 B
  __shared__ float  bias_l[DIM_C];

  const int t = threadIdx.x;

  for (int idx = t; idx < DIM_C * 32; idx += 256) {
    int n  = idx >> 5;
    int k4 = (idx & 31) << 2;
    float4 ws4 = *reinterpret_cast<const float4*>(Wself  + n * DIM_C + k4);
    float4 wn4 = *reinterpret_cast<const float4*>(Wneigh + n * DIM_C + k4);
    *reinterpret_cast<uint2*>(&Bl[n][k4]) =
        make_uint2(pack2(ws4.x, ws4.y), pack2(ws4.z, ws4.w));
    *reinterpret_cast<uint2*>(&Bl[n][128 + k4]) =
        make_uint2(pack2(wn4.x, wn4.y), pack2(wn4.z, wn4.w));
  }
  if (t < DIM_C) bias_l[t] = bias[t];
  __syncthreads();

  const int lane = t & 63;
  const int w    = t >> 6;
  const int am   = lane & 15;
  const int q    = lane >> 4;
  const int m0   = blockIdx.x * 64 + w * 16;

  int r = m0 + am;
  if (r >= N_NODES_C) r = N_NODES_C - 1;   // clamp; stores guarded below
  const ushort* aph = hb   + (size_t)r * DIM_C + q * 8;
  const ushort* apa = accb + (size_t)r * DIM_C + q * 8;

  f32x4 acc[8];
#pragma unroll
  for (int nt = 0; nt < 8; nt++) acc[nt] = (f32x4){0.f, 0.f, 0.f, 0.f};

#pragma unroll
  for (int ks = 0; ks < 4; ks++) {
    short8 af = *reinterpret_cast<const short8*>(aph + ks * 32);
#pragma unroll
    for (int nt = 0; nt < 8; nt++) {
      short8 bf = *reinterpret_cast<const short8*>(&Bl[nt * 16 + am][ks * 32 + q * 8]);
      acc[nt] = __builtin_amdgcn_mfma_f32_16x16x32_bf16(af, bf, acc[nt], 0, 0, 0);
    }
  }
#pragma unroll
  for (int ks = 0; ks < 4; ks++) {
    short8 af = *reinterpret_cast<const short8*>(apa + ks * 32);
#pragma unroll
    for (int nt = 0; nt < 8; nt++) {
      short8 bf = *reinterpret_cast<const short8*>(&Bl[nt * 16 + am][128 + ks * 32 + q * 8]);
      acc[nt] = __builtin_amdgcn_mfma_f32_16x16x32_bf16(af, bf, acc[nt], 0, 0, 0);
    }
  }

#pragma unroll
  for (int nt = 0; nt < 8; nt++) {
    int col = nt * 16 + am;
    float bv = bias_l[col];
#pragma unroll
    for (int rr = 0; rr < 4; rr++) {
      int row = m0 + q * 4 + rr;
      if (row < N_NODES_C) {
        float v = acc[nt][rr] + bv;
        out[(size_t)row * DIM_C + col] = fmaxf(v, 0.f);
      }
    }
  }
}

// --------------------------------------------------------------------------
extern "C" void kernel_launch(void* const* d_in, const int* in_sizes, int n_in,
                              void* d_out, int out_size, void* d_ws, size_t ws_size,
                              hipStream_t stream) {
  const float* h      = (const float*)d_in[0];
  const int*   src    = (const int*)d_in[1];
  const int*   dst    = (const int*)d_in[2];
  const float* deg    = (const float*)d_in[3];
  const float* Wself  = (const float*)d_in[4];
  const float* Wneigh = (const float*)d_in[5];
  const float* bias   = (const float*)d_in[6];
  float*       out    = (float*)d_out;

  char* ws = (char*)d_ws;
  ushort* hb   = (ushort*)ws;
  ushort* accb = (ushort*)(ws + OFF_ACC);
  int*    cnt  = (int*)(ws + OFF_CNT);
  int*    cur  = (int*)(ws + OFF_CUR);
  int*    offs = (int*)(ws + OFF_OFFS);
  int*    esrc = (int*)(ws + OFF_ESRC);

  // Zero cnt+cur (contiguous 400KB); everything else fully overwritten.
  hipMemsetAsync(cnt, 0, 2 * (size_t)N_NODES_C * sizeof(int), stream);

  sage_cast_hist<<<6250, 256, 0, stream>>>(h, hb, dst, cnt);
  sage_scan     <<<1, 1024, 0, stream>>>(cnt, offs);
  sage_place    <<<NCHUNK * P_PARTS, 256, 0, stream>>>(src, dst, offs, cur, esrc);
  sage_gather   <<<(N_NODES_C * 32) / 256, 256, 0, stream>>>(hb, offs, esrc, deg, accb);
  sage_gemm_mfma<<<(N_NODES_C + 63) / 64, 256, 0, stream>>>(hb, accb, Wself,
                                                            Wneigh, bias, out);
}